// Round 1
// baseline (624.324 us; speedup 1.0000x reference)
//
#include <hip/hip_runtime.h>
#include <math.h>

#define NG 2048
#define HH 128
#define WW 128
#define FOCAL 110.0f
#define NEARP 0.3f
#define EPSS 1e-4f
#define LOWPASS (0.3f / (110.0f * 110.0f))

// ws layout:
//   params  : float4[NG*3]          @ 0        (98304 B)  unsorted {u,v,ia,ib | ic,opa,r,g | b,0,0,0}
//   keys    : u64[NG]               @ 98304    (16384 B)
//   sorted  : float4[NG*3]          @ 114688   (98304 B)
#define WS_PARAMS_OFF 0
#define WS_KEYS_OFF   98304
#define WS_SORTED_OFF 114688

__global__ void splat_preprocess(const float* __restrict__ pos,
                                 const float* __restrict__ rgb,
                                 const float* __restrict__ opa,
                                 const float* __restrict__ quat,
                                 const float* __restrict__ scale,
                                 const float* __restrict__ w2c,
                                 const float* __restrict__ tran,
                                 float4* __restrict__ params,
                                 unsigned long long* __restrict__ keys) {
    int g = blockIdx.x * blockDim.x + threadIdx.x;
    if (g >= NG) return;

    float W00 = w2c[0], W01 = w2c[1], W02 = w2c[2];
    float W10 = w2c[3], W11 = w2c[4], W12 = w2c[5];
    float W20 = w2c[6], W21 = w2c[7], W22 = w2c[8];
    float t0 = tran[0], t1 = tran[1], t2 = tran[2];

    float px = pos[g * 3 + 0], py = pos[g * 3 + 1], pz = pos[g * 3 + 2];
    float cx = W00 * px + W01 * py + W02 * pz + t0;
    float cy = W10 * px + W11 * py + W12 * pz + t1;
    float cz = W20 * px + W21 * py + W22 * pz + t2;

    bool valid = cz > NEARP;
    float zs = valid ? cz : 1.0f;
    float u = cx / zs;
    float v = cy / zs;

    // quaternion -> R
    float qw = quat[g * 4 + 0], qx = quat[g * 4 + 1], qy = quat[g * 4 + 2], qz = quat[g * 4 + 3];
    float qn = sqrtf(qw * qw + qx * qx + qy * qy + qz * qz) + 1e-8f;
    float inv = 1.0f / qn;
    qw *= inv; qx *= inv; qy *= inv; qz *= inv;
    float R00 = 1.0f - 2.0f * (qy * qy + qz * qz);
    float R01 = 2.0f * (qx * qy - qw * qz);
    float R02 = 2.0f * (qx * qz + qw * qy);
    float R10 = 2.0f * (qx * qy + qw * qz);
    float R11 = 1.0f - 2.0f * (qx * qx + qz * qz);
    float R12 = 2.0f * (qy * qz - qw * qx);
    float R20 = 2.0f * (qx * qz - qw * qy);
    float R21 = 2.0f * (qy * qz + qw * qx);
    float R22 = 1.0f - 2.0f * (qx * qx + qy * qy);

    float s0 = fabsf(scale[g * 3 + 0]) + EPSS;
    float s1 = fabsf(scale[g * 3 + 1]) + EPSS;
    float s2 = fabsf(scale[g * 3 + 2]) + EPSS;

    // RS = R * diag(s) ; cov3 = RS RS^T (symmetric)
    float A00 = R00 * s0, A01 = R01 * s1, A02 = R02 * s2;
    float A10 = R10 * s0, A11 = R11 * s1, A12 = R12 * s2;
    float A20 = R20 * s0, A21 = R21 * s1, A22 = R22 * s2;
    float C00 = A00 * A00 + A01 * A01 + A02 * A02;
    float C01 = A00 * A10 + A01 * A11 + A02 * A12;
    float C02 = A00 * A20 + A01 * A21 + A02 * A22;
    float C11 = A10 * A10 + A11 * A11 + A12 * A12;
    float C12 = A10 * A20 + A11 * A21 + A12 * A22;
    float C22 = A20 * A20 + A21 * A21 + A22 * A22;

    // covc = W C W^T (symmetric) : B = W*C, M = B*W^T
    float B00 = W00 * C00 + W01 * C01 + W02 * C02;
    float B01 = W00 * C01 + W01 * C11 + W02 * C12;
    float B02 = W00 * C02 + W01 * C12 + W02 * C22;
    float B10 = W10 * C00 + W11 * C01 + W12 * C02;
    float B11 = W10 * C01 + W11 * C11 + W12 * C12;
    float B12 = W10 * C02 + W11 * C12 + W12 * C22;
    float B20 = W20 * C00 + W21 * C01 + W22 * C02;
    float B21 = W20 * C01 + W21 * C11 + W22 * C12;
    float B22 = W20 * C02 + W21 * C12 + W22 * C22;
    float M00 = B00 * W00 + B01 * W01 + B02 * W02;
    float M01 = B00 * W10 + B01 * W11 + B02 * W12;
    float M02 = B00 * W20 + B01 * W21 + B02 * W22;
    float M11 = B10 * W10 + B11 * W11 + B12 * W12;
    float M12 = B10 * W20 + B11 * W21 + B12 * W22;
    float M22 = B20 * W20 + B21 * W21 + B22 * W22;

    // cov2 = J M J^T with J = [[iz,0,-u*iz],[0,iz,-v*iz]]
    float iz = 1.0f / zs;
    float iz2 = iz * iz;
    float a = iz2 * (M00 - 2.0f * u * M02 + u * u * M22) + LOWPASS;
    float b = iz2 * (M01 - v * M02 - u * M12 + u * v * M22);
    float c = iz2 * (M11 - 2.0f * v * M12 + v * v * M22) + LOWPASS;

    float det = fmaxf(a * c - b * b, 1e-12f);
    float idet = 1.0f / det;
    float ia = c * idet;
    float ib = -b * idet;
    float ic = a * idet;

    float osig = valid ? (1.0f / (1.0f + expf(-opa[g]))) : 0.0f;
    float rr = 1.0f / (1.0f + expf(-rgb[g * 3 + 0]));
    float gg = 1.0f / (1.0f + expf(-rgb[g * 3 + 1]));
    float bb = 1.0f / (1.0f + expf(-rgb[g * 3 + 2]));

    params[g * 3 + 0] = make_float4(u, v, ia, ib);
    params[g * 3 + 1] = make_float4(ic, osig, rr, gg);
    params[g * 3 + 2] = make_float4(bb, 0.0f, 0.0f, 0.0f);

    unsigned int zb = valid ? __float_as_uint(cz) : 0x7f800000u;  // +inf for invalid
    keys[g] = ((unsigned long long)zb << 32) | (unsigned int)g;   // stable: index tiebreak
}

// Single-block bitonic sort of NG u64 keys in LDS, then reorder params.
__global__ __launch_bounds__(1024) void splat_sort_reorder(const unsigned long long* __restrict__ keys,
                                                           const float4* __restrict__ params,
                                                           float4* __restrict__ sorted) {
    __shared__ unsigned long long k[NG];
    int t = threadIdx.x;
    k[t] = keys[t];
    k[t + 1024] = keys[t + 1024];

    for (int size = 2; size <= NG; size <<= 1) {
        for (int stride = size >> 1; stride > 0; stride >>= 1) {
            __syncthreads();
            #pragma unroll
            for (int w = 0; w < 2; ++w) {
                int i = t + w * 1024;
                int ixj = i ^ stride;
                if (ixj > i) {
                    unsigned long long a = k[i], b = k[ixj];
                    bool up = ((i & size) == 0);
                    if (up ? (a > b) : (a < b)) { k[i] = b; k[ixj] = a; }
                }
            }
        }
    }
    __syncthreads();

    #pragma unroll
    for (int w = 0; w < 2; ++w) {
        int slot = t + w * 1024;
        int src = (int)(k[slot] & 0xffffffffu);
        sorted[slot * 3 + 0] = params[src * 3 + 0];
        sorted[slot * 3 + 1] = params[src * 3 + 1];
        sorted[slot * 3 + 2] = params[src * 3 + 2];
    }
}

// One thread per pixel; serial front-to-back over sorted gaussians.
// Gaussian params are wave-uniform per iteration -> scalar loads.
__global__ __launch_bounds__(64) void splat_render(const float4* __restrict__ sorted,
                                                   float* __restrict__ out) {
    int t = threadIdx.x;
    int bx = blockIdx.x & 15, by = blockIdx.x >> 4;
    int px = bx * 8 + (t & 7);
    int py = by * 8 + (t >> 3);
    float gu = ((float)px - (float)(WW / 2) + 0.5f) / FOCAL;
    float gv = ((float)py - (float)(HH / 2) + 0.5f) / FOCAL;

    float T = 1.0f, cr = 0.0f, cg = 0.0f, cb = 0.0f;

    for (int g = 0; g < NG; ++g) {
        float4 p0 = sorted[g * 3 + 0];  // u, v, ia, ib
        float4 p1 = sorted[g * 3 + 1];  // ic, opa, r, g
        float4 p2 = sorted[g * 3 + 2];  // b, -, -, -

        float dx = gu - p0.x;
        float dy = gv - p0.y;
        float power = -0.5f * (p0.z * dx * dx + p1.x * dy * dy) - p0.w * (dx * dy);
        power = fminf(power, 0.0f);
        float gw = __expf(power);
        float alpha = fminf(p1.y * gw, 0.99f);
        float w = alpha * T;
        cr = fmaf(w, p1.z, cr);
        cg = fmaf(w, p1.w, cg);
        cb = fmaf(w, p2.x, cb);
        T = T * (1.0f - alpha);

        if ((g & 15) == 15) {
            if (__all(T < 1e-5f)) break;
        }
    }

    int p = py * WW + px;
    out[p * 3 + 0] = cr;
    out[p * 3 + 1] = cg;
    out[p * 3 + 2] = cb;
}

extern "C" void kernel_launch(void* const* d_in, const int* in_sizes, int n_in,
                              void* d_out, int out_size, void* d_ws, size_t ws_size,
                              hipStream_t stream) {
    const float* pos   = (const float*)d_in[0];
    const float* rgb   = (const float*)d_in[1];
    const float* opa   = (const float*)d_in[2];
    const float* quat  = (const float*)d_in[3];
    const float* scale = (const float*)d_in[4];
    const float* w2c   = (const float*)d_in[5];
    const float* tran  = (const float*)d_in[6];
    float* out = (float*)d_out;

    char* ws = (char*)d_ws;
    float4* params = (float4*)(ws + WS_PARAMS_OFF);
    unsigned long long* keys = (unsigned long long*)(ws + WS_KEYS_OFF);
    float4* sorted = (float4*)(ws + WS_SORTED_OFF);

    splat_preprocess<<<(NG + 255) / 256, 256, 0, stream>>>(pos, rgb, opa, quat, scale, w2c, tran,
                                                           params, keys);
    splat_sort_reorder<<<1, 1024, 0, stream>>>(keys, params, sorted);
    splat_render<<<(HH * WW) / 64, 64, 0, stream>>>(sorted, out);
}

// Round 2
// 76.530 us; speedup vs baseline: 8.1580x; 8.1580x over previous
//
#include <hip/hip_runtime.h>
#include <math.h>

#define NG 2048
#define HH 128
#define WW 128
#define FOCAL 110.0f
#define NEARP 0.3f
#define EPSS 1e-4f
#define LOWPASS (0.3f / (110.0f * 110.0f))

#define NSEG 16
#define SEGLEN (NG / NSEG)   // 128

// ws layout:
//   params  : float4[NG*3]          @ 0        (98304 B)  unsorted {u,v,ia,ib | ic,opa,r,g | b,0,0,0}
//   keys    : u64[NG]               @ 98304    (16384 B)
//   sorted  : float4[NG*3]          @ 114688   (98304 B)
#define WS_PARAMS_OFF 0
#define WS_KEYS_OFF   98304
#define WS_SORTED_OFF 114688

__global__ void splat_preprocess(const float* __restrict__ pos,
                                 const float* __restrict__ rgb,
                                 const float* __restrict__ opa,
                                 const float* __restrict__ quat,
                                 const float* __restrict__ scale,
                                 const float* __restrict__ w2c,
                                 const float* __restrict__ tran,
                                 float4* __restrict__ params,
                                 unsigned long long* __restrict__ keys) {
    int g = blockIdx.x * blockDim.x + threadIdx.x;
    if (g >= NG) return;

    float W00 = w2c[0], W01 = w2c[1], W02 = w2c[2];
    float W10 = w2c[3], W11 = w2c[4], W12 = w2c[5];
    float W20 = w2c[6], W21 = w2c[7], W22 = w2c[8];
    float t0 = tran[0], t1 = tran[1], t2 = tran[2];

    float px = pos[g * 3 + 0], py = pos[g * 3 + 1], pz = pos[g * 3 + 2];
    float cx = W00 * px + W01 * py + W02 * pz + t0;
    float cy = W10 * px + W11 * py + W12 * pz + t1;
    float cz = W20 * px + W21 * py + W22 * pz + t2;

    bool valid = cz > NEARP;
    float zs = valid ? cz : 1.0f;
    float u = cx / zs;
    float v = cy / zs;

    // quaternion -> R
    float qw = quat[g * 4 + 0], qx = quat[g * 4 + 1], qy = quat[g * 4 + 2], qz = quat[g * 4 + 3];
    float qn = sqrtf(qw * qw + qx * qx + qy * qy + qz * qz) + 1e-8f;
    float inv = 1.0f / qn;
    qw *= inv; qx *= inv; qy *= inv; qz *= inv;
    float R00 = 1.0f - 2.0f * (qy * qy + qz * qz);
    float R01 = 2.0f * (qx * qy - qw * qz);
    float R02 = 2.0f * (qx * qz + qw * qy);
    float R10 = 2.0f * (qx * qy + qw * qz);
    float R11 = 1.0f - 2.0f * (qx * qx + qz * qz);
    float R12 = 2.0f * (qy * qz - qw * qx);
    float R20 = 2.0f * (qx * qz - qw * qy);
    float R21 = 2.0f * (qy * qz + qw * qx);
    float R22 = 1.0f - 2.0f * (qx * qx + qy * qy);

    float s0 = fabsf(scale[g * 3 + 0]) + EPSS;
    float s1 = fabsf(scale[g * 3 + 1]) + EPSS;
    float s2 = fabsf(scale[g * 3 + 2]) + EPSS;

    // RS = R * diag(s) ; cov3 = RS RS^T (symmetric)
    float A00 = R00 * s0, A01 = R01 * s1, A02 = R02 * s2;
    float A10 = R10 * s0, A11 = R11 * s1, A12 = R12 * s2;
    float A20 = R20 * s0, A21 = R21 * s1, A22 = R22 * s2;
    float C00 = A00 * A00 + A01 * A01 + A02 * A02;
    float C01 = A00 * A10 + A01 * A11 + A02 * A12;
    float C02 = A00 * A20 + A01 * A21 + A02 * A22;
    float C11 = A10 * A10 + A11 * A11 + A12 * A12;
    float C12 = A10 * A20 + A11 * A21 + A12 * A22;
    float C22 = A20 * A20 + A21 * A21 + A22 * A22;

    // covc = W C W^T (symmetric)
    float B00 = W00 * C00 + W01 * C01 + W02 * C02;
    float B01 = W00 * C01 + W01 * C11 + W02 * C12;
    float B02 = W00 * C02 + W01 * C12 + W02 * C22;
    float B10 = W10 * C00 + W11 * C01 + W12 * C02;
    float B11 = W10 * C01 + W11 * C11 + W12 * C12;
    float B12 = W10 * C02 + W11 * C12 + W12 * C22;
    float B20 = W20 * C00 + W21 * C01 + W22 * C02;
    float B21 = W20 * C01 + W21 * C11 + W22 * C12;
    float B22 = W20 * C02 + W21 * C12 + W22 * C22;
    float M00 = B00 * W00 + B01 * W01 + B02 * W02;
    float M01 = B00 * W10 + B01 * W11 + B02 * W12;
    float M02 = B00 * W20 + B01 * W21 + B02 * W22;
    float M11 = B10 * W10 + B11 * W11 + B12 * W12;
    float M12 = B10 * W20 + B11 * W21 + B12 * W22;
    float M22 = B20 * W20 + B21 * W21 + B22 * W22;

    // cov2 = J M J^T with J = [[iz,0,-u*iz],[0,iz,-v*iz]]
    float iz = 1.0f / zs;
    float iz2 = iz * iz;
    float a = iz2 * (M00 - 2.0f * u * M02 + u * u * M22) + LOWPASS;
    float b = iz2 * (M01 - v * M02 - u * M12 + u * v * M22);
    float c = iz2 * (M11 - 2.0f * v * M12 + v * v * M22) + LOWPASS;

    float det = fmaxf(a * c - b * b, 1e-12f);
    float idet = 1.0f / det;
    float ia = c * idet;
    float ib = -b * idet;
    float ic = a * idet;

    float osig = valid ? (1.0f / (1.0f + expf(-opa[g]))) : 0.0f;
    float rr = 1.0f / (1.0f + expf(-rgb[g * 3 + 0]));
    float gg = 1.0f / (1.0f + expf(-rgb[g * 3 + 1]));
    float bb = 1.0f / (1.0f + expf(-rgb[g * 3 + 2]));

    params[g * 3 + 0] = make_float4(u, v, ia, ib);
    params[g * 3 + 1] = make_float4(ic, osig, rr, gg);
    params[g * 3 + 2] = make_float4(bb, 0.0f, 0.0f, 0.0f);

    unsigned int zb = valid ? __float_as_uint(cz) : 0x7f800000u;  // +inf for invalid
    keys[g] = ((unsigned long long)zb << 32) | (unsigned int)g;   // stable: index tiebreak
}

// Single-block bitonic sort of NG u64 keys in LDS, then reorder params.
__global__ __launch_bounds__(1024) void splat_sort_reorder(const unsigned long long* __restrict__ keys,
                                                           const float4* __restrict__ params,
                                                           float4* __restrict__ sorted) {
    __shared__ unsigned long long k[NG];
    int t = threadIdx.x;
    k[t] = keys[t];
    k[t + 1024] = keys[t + 1024];

    for (int size = 2; size <= NG; size <<= 1) {
        for (int stride = size >> 1; stride > 0; stride >>= 1) {
            __syncthreads();
            #pragma unroll
            for (int w = 0; w < 2; ++w) {
                int i = t + w * 1024;
                int ixj = i ^ stride;
                if (ixj > i) {
                    unsigned long long a = k[i], b = k[ixj];
                    bool up = ((i & size) == 0);
                    if (up ? (a > b) : (a < b)) { k[i] = b; k[ixj] = a; }
                }
            }
        }
    }
    __syncthreads();

    #pragma unroll
    for (int w = 0; w < 2; ++w) {
        int slot = t + w * 1024;
        int src = (int)(k[slot] & 0xffffffffu);
        sorted[slot * 3 + 0] = params[src * 3 + 0];
        sorted[slot * 3 + 1] = params[src * 3 + 1];
        sorted[slot * 3 + 2] = params[src * 3 + 2];
    }
}

// Segmented render: block = 1024 threads = 16 waves, one 8x8 pixel tile.
// Wave w composites gaussian segment [w*128, (w+1)*128) for all 64 pixels
// (segment-local T starts at 1). Segments combine associatively in LDS:
//   C = C_a + T_a*C_b ; T = T_a*T_b   (in depth order)
__global__ __launch_bounds__(1024) void splat_render(const float4* __restrict__ sorted,
                                                     float* __restrict__ out) {
    __shared__ float4 seg[NSEG][64];

    int t = threadIdx.x;
    int lane = t & 63;
    int wave = t >> 6;

    int bx = blockIdx.x & 15, by = blockIdx.x >> 4;
    int px = bx * 8 + (lane & 7);
    int py = by * 8 + (lane >> 3);
    float gu = ((float)px - (float)(WW / 2) + 0.5f) / FOCAL;
    float gv = ((float)py - (float)(HH / 2) + 0.5f) / FOCAL;

    float T = 1.0f, cr = 0.0f, cg = 0.0f, cb = 0.0f;

    int g0 = wave * SEGLEN;
    #pragma unroll 4
    for (int g = g0; g < g0 + SEGLEN; ++g) {
        float4 p0 = sorted[g * 3 + 0];  // u, v, ia, ib
        float4 p1 = sorted[g * 3 + 1];  // ic, opa, r, g
        float4 p2 = sorted[g * 3 + 2];  // b, -, -, -

        float dx = gu - p0.x;
        float dy = gv - p0.y;
        float power = -0.5f * (p0.z * dx * dx + p1.x * dy * dy) - p0.w * (dx * dy);
        power = fminf(power, 0.0f);
        float gw = __expf(power);
        float alpha = fminf(p1.y * gw, 0.99f);
        float w = alpha * T;
        cr = fmaf(w, p1.z, cr);
        cg = fmaf(w, p1.w, cg);
        cb = fmaf(w, p2.x, cb);
        T = T * (1.0f - alpha);
    }

    seg[wave][lane] = make_float4(cr, cg, cb, T);
    __syncthreads();

    if (t < 64) {
        float Tt = 1.0f, r = 0.0f, g = 0.0f, b = 0.0f;
        #pragma unroll
        for (int s = 0; s < NSEG; ++s) {
            float4 v = seg[s][t];
            r = fmaf(Tt, v.x, r);
            g = fmaf(Tt, v.y, g);
            b = fmaf(Tt, v.z, b);
            Tt *= v.w;
        }
        int p = py * WW + px;
        out[p * 3 + 0] = r;
        out[p * 3 + 1] = g;
        out[p * 3 + 2] = b;
    }
}

extern "C" void kernel_launch(void* const* d_in, const int* in_sizes, int n_in,
                              void* d_out, int out_size, void* d_ws, size_t ws_size,
                              hipStream_t stream) {
    const float* pos   = (const float*)d_in[0];
    const float* rgb   = (const float*)d_in[1];
    const float* opa   = (const float*)d_in[2];
    const float* quat  = (const float*)d_in[3];
    const float* scale = (const float*)d_in[4];
    const float* w2c   = (const float*)d_in[5];
    const float* tran  = (const float*)d_in[6];
    float* out = (float*)d_out;

    char* ws = (char*)d_ws;
    float4* params = (float4*)(ws + WS_PARAMS_OFF);
    unsigned long long* keys = (unsigned long long*)(ws + WS_KEYS_OFF);
    float4* sorted = (float4*)(ws + WS_SORTED_OFF);

    splat_preprocess<<<(NG + 255) / 256, 256, 0, stream>>>(pos, rgb, opa, quat, scale, w2c, tran,
                                                           params, keys);
    splat_sort_reorder<<<1, 1024, 0, stream>>>(keys, params, sorted);
    splat_render<<<(HH * WW) / 64, 1024, 0, stream>>>(sorted, out);
}

// Round 3
// 35.168 us; speedup vs baseline: 17.7527x; 2.1761x over previous
//
#include <hip/hip_runtime.h>
#include <math.h>

#define NG 2048
#define HH 128
#define WW 128
#define FOCAL 110.0f
#define NEARP 0.3f
#define EPSS 1e-4f
#define LOWPASS (0.3f / (110.0f * 110.0f))
#define L2E 1.4426950408889634f

#define NSEG 16
#define SEGLEN (NG / NSEG)   // 128

// ws layout:
//   params  : float4[NG*3]  @ 0        {u,v,A,B | C,osig,r,g | b,0,0,0}  (A,B,C have -0.5*log2e folded)
//   keys    : u64[NG]       @ 98304
//   sorted  : float4[NG*3]  @ 114688
#define WS_PARAMS_OFF 0
#define WS_KEYS_OFF   98304
#define WS_SORTED_OFF 114688

#if defined(__has_builtin) && __has_builtin(__builtin_amdgcn_exp2f)
#define EXP2F(x) __builtin_amdgcn_exp2f(x)
#else
#define EXP2F(x) exp2f(x)
#endif

__global__ void splat_preprocess(const float* __restrict__ pos,
                                 const float* __restrict__ rgb,
                                 const float* __restrict__ opa,
                                 const float* __restrict__ quat,
                                 const float* __restrict__ scale,
                                 const float* __restrict__ w2c,
                                 const float* __restrict__ tran,
                                 float4* __restrict__ params,
                                 unsigned long long* __restrict__ keys) {
    int g = blockIdx.x * blockDim.x + threadIdx.x;
    if (g >= NG) return;

    float W00 = w2c[0], W01 = w2c[1], W02 = w2c[2];
    float W10 = w2c[3], W11 = w2c[4], W12 = w2c[5];
    float W20 = w2c[6], W21 = w2c[7], W22 = w2c[8];
    float t0 = tran[0], t1 = tran[1], t2 = tran[2];

    float px = pos[g * 3 + 0], py = pos[g * 3 + 1], pz = pos[g * 3 + 2];
    float cx = W00 * px + W01 * py + W02 * pz + t0;
    float cy = W10 * px + W11 * py + W12 * pz + t1;
    float cz = W20 * px + W21 * py + W22 * pz + t2;

    bool valid = cz > NEARP;
    float zs = valid ? cz : 1.0f;
    float u = cx / zs;
    float v = cy / zs;

    // quaternion -> R
    float qw = quat[g * 4 + 0], qx = quat[g * 4 + 1], qy = quat[g * 4 + 2], qz = quat[g * 4 + 3];
    float qn = sqrtf(qw * qw + qx * qx + qy * qy + qz * qz) + 1e-8f;
    float inv = 1.0f / qn;
    qw *= inv; qx *= inv; qy *= inv; qz *= inv;
    float R00 = 1.0f - 2.0f * (qy * qy + qz * qz);
    float R01 = 2.0f * (qx * qy - qw * qz);
    float R02 = 2.0f * (qx * qz + qw * qy);
    float R10 = 2.0f * (qx * qy + qw * qz);
    float R11 = 1.0f - 2.0f * (qx * qx + qz * qz);
    float R12 = 2.0f * (qy * qz - qw * qx);
    float R20 = 2.0f * (qx * qz - qw * qy);
    float R21 = 2.0f * (qy * qz + qw * qx);
    float R22 = 1.0f - 2.0f * (qx * qx + qy * qy);

    float s0 = fabsf(scale[g * 3 + 0]) + EPSS;
    float s1 = fabsf(scale[g * 3 + 1]) + EPSS;
    float s2 = fabsf(scale[g * 3 + 2]) + EPSS;

    // cov3 = (R diag(s)) (R diag(s))^T
    float A00 = R00 * s0, A01 = R01 * s1, A02 = R02 * s2;
    float A10 = R10 * s0, A11 = R11 * s1, A12 = R12 * s2;
    float A20 = R20 * s0, A21 = R21 * s1, A22 = R22 * s2;
    float C00 = A00 * A00 + A01 * A01 + A02 * A02;
    float C01 = A00 * A10 + A01 * A11 + A02 * A12;
    float C02 = A00 * A20 + A01 * A21 + A02 * A22;
    float C11 = A10 * A10 + A11 * A11 + A12 * A12;
    float C12 = A10 * A20 + A11 * A21 + A12 * A22;
    float C22 = A20 * A20 + A21 * A21 + A22 * A22;

    // covc = W cov3 W^T
    float B00 = W00 * C00 + W01 * C01 + W02 * C02;
    float B01 = W00 * C01 + W01 * C11 + W02 * C12;
    float B02 = W00 * C02 + W01 * C12 + W02 * C22;
    float B10 = W10 * C00 + W11 * C01 + W12 * C02;
    float B11 = W10 * C01 + W11 * C11 + W12 * C12;
    float B12 = W10 * C02 + W11 * C12 + W12 * C22;
    float B20 = W20 * C00 + W21 * C01 + W22 * C02;
    float B21 = W20 * C01 + W21 * C11 + W22 * C12;
    float B22 = W20 * C02 + W21 * C12 + W22 * C22;
    float M00 = B00 * W00 + B01 * W01 + B02 * W02;
    float M01 = B00 * W10 + B01 * W11 + B02 * W12;
    float M02 = B00 * W20 + B01 * W21 + B02 * W22;
    float M11 = B10 * W10 + B11 * W11 + B12 * W12;
    float M12 = B10 * W20 + B11 * W21 + B12 * W22;
    float M22 = B20 * W20 + B21 * W21 + B22 * W22;

    // cov2 = J covc J^T
    float iz = 1.0f / zs;
    float iz2 = iz * iz;
    float a = iz2 * (M00 - 2.0f * u * M02 + u * u * M22) + LOWPASS;
    float b = iz2 * (M01 - v * M02 - u * M12 + u * v * M22);
    float c = iz2 * (M11 - 2.0f * v * M12 + v * v * M22) + LOWPASS;

    float det = fmaxf(a * c - b * b, 1e-12f);
    float idet = 1.0f / det;
    float ia = c * idet;
    float ib = -b * idet;
    float ic = a * idet;

    // fold -0.5 and log2(e) into the conic:
    // power_log2 = (Af*dx + Bf*dy)*dx + Cf*dy*dy ; gw = exp2(min(power_log2,0))
    float Af = -0.5f * L2E * ia;
    float Bf = -L2E * ib;
    float Cf = -0.5f * L2E * ic;

    float osig = valid ? (1.0f / (1.0f + expf(-opa[g]))) : 0.0f;
    float rr = 1.0f / (1.0f + expf(-rgb[g * 3 + 0]));
    float gg = 1.0f / (1.0f + expf(-rgb[g * 3 + 1]));
    float bb = 1.0f / (1.0f + expf(-rgb[g * 3 + 2]));

    params[g * 3 + 0] = make_float4(u, v, Af, Bf);
    params[g * 3 + 1] = make_float4(Cf, osig, rr, gg);
    params[g * 3 + 2] = make_float4(bb, 0.0f, 0.0f, 0.0f);

    unsigned int zb = valid ? __float_as_uint(cz) : 0x7f800000u;  // +inf for invalid
    keys[g] = ((unsigned long long)zb << 32) | (unsigned int)g;   // unique, stable
}

// Rank-based stable counting sort: rank[i] = #{j : key[j] < key[i]} (keys unique).
// 32 blocks x 1024 threads; block handles i in [blk*64, blk*64+64) by lane,
// wave w counts over j-chunk [w*128, w*128+128) from LDS; reduce; scatter.
__global__ __launch_bounds__(1024) void splat_rank_scatter(const unsigned long long* __restrict__ keys,
                                                           const float4* __restrict__ params,
                                                           float4* __restrict__ sorted) {
    __shared__ unsigned long long lk[NG];   // 16 KB
    __shared__ int partial[16][64];         // 4 KB

    int t = threadIdx.x;
    lk[t] = keys[t];
    lk[t + 1024] = keys[t + 1024];
    __syncthreads();

    int lane = t & 63;
    int wave = t >> 6;
    int i = blockIdx.x * 64 + lane;
    unsigned long long ki = lk[i];

    int cnt = 0;
    int j0 = wave * 128;
    #pragma unroll 8
    for (int j = j0; j < j0 + 128; ++j) cnt += (lk[j] < ki) ? 1 : 0;
    partial[wave][lane] = cnt;
    __syncthreads();

    if (t < 64) {
        int rank = 0;
        #pragma unroll
        for (int s = 0; s < 16; ++s) rank += partial[s][t];
        int src = blockIdx.x * 64 + t;
        sorted[rank * 3 + 0] = params[src * 3 + 0];
        sorted[rank * 3 + 1] = params[src * 3 + 1];
        sorted[rank * 3 + 2] = params[src * 3 + 2];
    }
}

// Segmented render: block = 16 waves, one 8x8 tile. Wave w composites
// segment [w*128,(w+1)*128) with segment-local T, ordered combine in LDS.
__global__ __launch_bounds__(1024) void splat_render(const float4* __restrict__ sorted,
                                                     float* __restrict__ out) {
    __shared__ float4 seg[NSEG][64];

    int t = threadIdx.x;
    int lane = t & 63;
    int wave = __builtin_amdgcn_readfirstlane(t >> 6);   // SGPR -> scalar loads below

    int bx = blockIdx.x & 15, by = blockIdx.x >> 4;
    int px = bx * 8 + (lane & 7);
    int py = by * 8 + (lane >> 3);
    float gu = ((float)px - (float)(WW / 2) + 0.5f) / FOCAL;
    float gv = ((float)py - (float)(HH / 2) + 0.5f) / FOCAL;

    const float4* __restrict__ sp = sorted + (size_t)wave * SEGLEN * 3;

    float T = 1.0f, cr = 0.0f, cg = 0.0f, cb = 0.0f;

    #pragma unroll 4
    for (int g = 0; g < SEGLEN; ++g) {
        float4 p0 = sp[g * 3 + 0];  // u, v, A, B
        float4 p1 = sp[g * 3 + 1];  // C, osig, r, g
        float4 p2 = sp[g * 3 + 2];  // b, -, -, -

        float dx = gu - p0.x;
        float dy = gv - p0.y;
        float t1 = fmaf(p0.w, dy, p0.z * dx);
        float p  = fmaf(t1, dx, p1.x * (dy * dy));
        p = fminf(p, 0.0f);
        float gw = EXP2F(p);
        float alpha = fminf(p1.y * gw, 0.99f);
        float w = alpha * T;
        cr = fmaf(w, p1.z, cr);
        cg = fmaf(w, p1.w, cg);
        cb = fmaf(w, p2.x, cb);
        T = fmaf(-alpha, T, T);
    }

    seg[wave][lane] = make_float4(cr, cg, cb, T);
    __syncthreads();

    if (t < 64) {
        float Tt = 1.0f, r = 0.0f, g = 0.0f, b = 0.0f;
        #pragma unroll
        for (int s = 0; s < NSEG; ++s) {
            float4 v = seg[s][t];
            r = fmaf(Tt, v.x, r);
            g = fmaf(Tt, v.y, g);
            b = fmaf(Tt, v.z, b);
            Tt *= v.w;
        }
        int p = py * WW + px;
        out[p * 3 + 0] = r;
        out[p * 3 + 1] = g;
        out[p * 3 + 2] = b;
    }
}

extern "C" void kernel_launch(void* const* d_in, const int* in_sizes, int n_in,
                              void* d_out, int out_size, void* d_ws, size_t ws_size,
                              hipStream_t stream) {
    const float* pos   = (const float*)d_in[0];
    const float* rgb   = (const float*)d_in[1];
    const float* opa   = (const float*)d_in[2];
    const float* quat  = (const float*)d_in[3];
    const float* scale = (const float*)d_in[4];
    const float* w2c   = (const float*)d_in[5];
    const float* tran  = (const float*)d_in[6];
    float* out = (float*)d_out;

    char* ws = (char*)d_ws;
    float4* params = (float4*)(ws + WS_PARAMS_OFF);
    unsigned long long* keys = (unsigned long long*)(ws + WS_KEYS_OFF);
    float4* sorted = (float4*)(ws + WS_SORTED_OFF);

    splat_preprocess<<<(NG + 255) / 256, 256, 0, stream>>>(pos, rgb, opa, quat, scale, w2c, tran,
                                                           params, keys);
    splat_rank_scatter<<<NG / 64, 1024, 0, stream>>>(keys, params, sorted);
    splat_render<<<(HH * WW) / 64, 1024, 0, stream>>>(sorted, out);
}

// Round 4
// 19.519 us; speedup vs baseline: 31.9858x; 1.8017x over previous
//
#include <hip/hip_runtime.h>
#include <math.h>

#define NG 2048
#define HH 128
#define WW 128
#define FOCAL 110.0f
#define NEARP 0.3f
#define EPSS 1e-4f
#define LOWPASS (0.3f / (110.0f * 110.0f))
#define L2E 1.4426950408889634f
#define LN_INV_ACUT 11.512925465f   // ln(1e5): alpha cutoff 1e-5

#define NSEG 16
#define SEGLEN (NG / NSEG)   // 128

// ws layout:
//   params : float4[NG*3] @ 0       {u,v,A,B | C,osig,r,g | b,0,0,0} (A,B,C folded with -0.5*log2e)
//   bbox   : float4[NG]   @ 98304   {u,v,ru,rv}
//   keys   : u64[NG]      @ 131072
//   sorted : float4[NG*3] @ 147456
//   sbbox  : float4[NG]   @ 245760
#define WS_PARAMS_OFF 0
#define WS_BBOX_OFF   98304
#define WS_KEYS_OFF   131072
#define WS_SORTED_OFF 147456
#define WS_SBBOX_OFF  245760

#if defined(__has_builtin) && __has_builtin(__builtin_amdgcn_exp2f)
#define EXP2F(x) __builtin_amdgcn_exp2f(x)
#else
#define EXP2F(x) exp2f(x)
#endif

__global__ void splat_preprocess(const float* __restrict__ pos,
                                 const float* __restrict__ rgb,
                                 const float* __restrict__ opa,
                                 const float* __restrict__ quat,
                                 const float* __restrict__ scale,
                                 const float* __restrict__ w2c,
                                 const float* __restrict__ tran,
                                 float4* __restrict__ params,
                                 float4* __restrict__ bbox,
                                 unsigned long long* __restrict__ keys) {
    int g = blockIdx.x * blockDim.x + threadIdx.x;
    if (g >= NG) return;

    float W00 = w2c[0], W01 = w2c[1], W02 = w2c[2];
    float W10 = w2c[3], W11 = w2c[4], W12 = w2c[5];
    float W20 = w2c[6], W21 = w2c[7], W22 = w2c[8];
    float t0 = tran[0], t1 = tran[1], t2 = tran[2];

    float px = pos[g * 3 + 0], py = pos[g * 3 + 1], pz = pos[g * 3 + 2];
    float cx = W00 * px + W01 * py + W02 * pz + t0;
    float cy = W10 * px + W11 * py + W12 * pz + t1;
    float cz = W20 * px + W21 * py + W22 * pz + t2;

    bool valid = cz > NEARP;
    float zs = valid ? cz : 1.0f;
    float u = cx / zs;
    float v = cy / zs;

    // quaternion -> R
    float qw = quat[g * 4 + 0], qx = quat[g * 4 + 1], qy = quat[g * 4 + 2], qz = quat[g * 4 + 3];
    float qn = sqrtf(qw * qw + qx * qx + qy * qy + qz * qz) + 1e-8f;
    float inv = 1.0f / qn;
    qw *= inv; qx *= inv; qy *= inv; qz *= inv;
    float R00 = 1.0f - 2.0f * (qy * qy + qz * qz);
    float R01 = 2.0f * (qx * qy - qw * qz);
    float R02 = 2.0f * (qx * qz + qw * qy);
    float R10 = 2.0f * (qx * qy + qw * qz);
    float R11 = 1.0f - 2.0f * (qx * qx + qz * qz);
    float R12 = 2.0f * (qy * qz - qw * qx);
    float R20 = 2.0f * (qx * qz - qw * qy);
    float R21 = 2.0f * (qy * qz + qw * qx);
    float R22 = 1.0f - 2.0f * (qx * qx + qy * qy);

    float s0 = fabsf(scale[g * 3 + 0]) + EPSS;
    float s1 = fabsf(scale[g * 3 + 1]) + EPSS;
    float s2 = fabsf(scale[g * 3 + 2]) + EPSS;

    // cov3 = (R diag(s)) (R diag(s))^T
    float A00 = R00 * s0, A01 = R01 * s1, A02 = R02 * s2;
    float A10 = R10 * s0, A11 = R11 * s1, A12 = R12 * s2;
    float A20 = R20 * s0, A21 = R21 * s1, A22 = R22 * s2;
    float C00 = A00 * A00 + A01 * A01 + A02 * A02;
    float C01 = A00 * A10 + A01 * A11 + A02 * A12;
    float C02 = A00 * A20 + A01 * A21 + A02 * A22;
    float C11 = A10 * A10 + A11 * A11 + A12 * A12;
    float C12 = A10 * A20 + A11 * A21 + A12 * A22;
    float C22 = A20 * A20 + A21 * A21 + A22 * A22;

    // covc = W cov3 W^T
    float B00 = W00 * C00 + W01 * C01 + W02 * C02;
    float B01 = W00 * C01 + W01 * C11 + W02 * C12;
    float B02 = W00 * C02 + W01 * C12 + W02 * C22;
    float B10 = W10 * C00 + W11 * C01 + W12 * C02;
    float B11 = W10 * C01 + W11 * C11 + W12 * C12;
    float B12 = W10 * C02 + W11 * C12 + W12 * C22;
    float B20 = W20 * C00 + W21 * C01 + W22 * C02;
    float B21 = W20 * C01 + W21 * C11 + W22 * C12;
    float B22 = W20 * C02 + W21 * C12 + W22 * C22;
    float M00 = B00 * W00 + B01 * W01 + B02 * W02;
    float M01 = B00 * W10 + B01 * W11 + B02 * W12;
    float M02 = B00 * W20 + B01 * W21 + B02 * W22;
    float M11 = B10 * W10 + B11 * W11 + B12 * W12;
    float M12 = B10 * W20 + B11 * W21 + B12 * W22;
    float M22 = B20 * W20 + B21 * W21 + B22 * W22;

    // cov2 = J covc J^T
    float iz = 1.0f / zs;
    float iz2 = iz * iz;
    float a = iz2 * (M00 - 2.0f * u * M02 + u * u * M22) + LOWPASS;
    float b = iz2 * (M01 - v * M02 - u * M12 + u * v * M22);
    float c = iz2 * (M11 - 2.0f * v * M12 + v * v * M22) + LOWPASS;

    float det = fmaxf(a * c - b * b, 1e-12f);
    float idet = 1.0f / det;
    float ia = c * idet;
    float ib = -b * idet;
    float ic = a * idet;

    // folded conic: power_log2 = (Af*dx + Bf*dy)*dx + Cf*dy*dy
    float Af = -0.5f * L2E * ia;
    float Bf = -L2E * ib;
    float Cf = -0.5f * L2E * ic;

    float osig = valid ? (1.0f / (1.0f + expf(-opa[g]))) : 0.0f;
    float rr = 1.0f / (1.0f + expf(-rgb[g * 3 + 0]));
    float gg = 1.0f / (1.0f + expf(-rgb[g * 3 + 1]));
    float bb = 1.0f / (1.0f + expf(-rgb[g * 3 + 2]));

    params[g * 3 + 0] = make_float4(u, v, Af, Bf);
    params[g * 3 + 1] = make_float4(Cf, osig, rr, gg);
    params[g * 3 + 2] = make_float4(bb, 0.0f, 0.0f, 0.0f);

    // conservative bbox: alpha >= 1e-5  <=>  Q <= tau ;  |dx|max = sqrt(tau*a)
    float tau = 2.0f * (logf(osig) + LN_INV_ACUT);   // osig=0 -> -inf -> culled
    float ru, rv;
    if (valid && tau > 0.0f) {
        ru = sqrtf(tau * a);
        rv = sqrtf(tau * c);
    } else {
        ru = -1e30f;
        rv = -1e30f;
    }
    bbox[g] = make_float4(u, v, ru, rv);

    unsigned int zb = valid ? __float_as_uint(cz) : 0x7f800000u;  // +inf for invalid
    keys[g] = ((unsigned long long)zb << 32) | (unsigned int)g;   // unique, stable
}

// Rank-based stable counting sort: rank[i] = #{j : key[j] < key[i]} (keys unique).
__global__ __launch_bounds__(1024) void splat_rank_scatter(const unsigned long long* __restrict__ keys,
                                                           const float4* __restrict__ params,
                                                           const float4* __restrict__ bbox,
                                                           float4* __restrict__ sorted,
                                                           float4* __restrict__ sbbox) {
    __shared__ unsigned long long lk[NG];   // 16 KB
    __shared__ int partial[16][64];         // 4 KB

    int t = threadIdx.x;
    lk[t] = keys[t];
    lk[t + 1024] = keys[t + 1024];
    __syncthreads();

    int lane = t & 63;
    int wave = t >> 6;
    int i = blockIdx.x * 64 + lane;
    unsigned long long ki = lk[i];

    int cnt = 0;
    int j0 = wave * 128;
    #pragma unroll 8
    for (int j = j0; j < j0 + 128; ++j) cnt += (lk[j] < ki) ? 1 : 0;
    partial[wave][lane] = cnt;
    __syncthreads();

    if (t < 64) {
        int rank = 0;
        #pragma unroll
        for (int s = 0; s < 16; ++s) rank += partial[s][t];
        int src = blockIdx.x * 64 + t;
        sorted[rank * 3 + 0] = params[src * 3 + 0];
        sorted[rank * 3 + 1] = params[src * 3 + 1];
        sorted[rank * 3 + 2] = params[src * 3 + 2];
        sbbox[rank] = bbox[src];
    }
}

// Tiled render: block = 1024 threads = 16 waves, one 8x8 tile.
// Phase 1: cull NG gaussians against tile bbox, ballot-compact surviving
//          indices into depth-ordered LDS list.
// Phase 2: waves composite contiguous chunks of the list (segment-local T),
//          ordered associative combine in LDS.
__global__ __launch_bounds__(1024) void splat_render(const float4* __restrict__ sbbox,
                                                     const float4* __restrict__ sorted,
                                                     float* __restrict__ out) {
    __shared__ unsigned short list[NG];     // 4 KB
    __shared__ int wcnt[NSEG];
    __shared__ float4 seg[NSEG][64];        // 4 KB

    int t = threadIdx.x;
    int lane = t & 63;
    int wave = t >> 6;

    int bx = blockIdx.x & 15, by = blockIdx.x >> 4;

    // tile center/half-width in uv (pixel centers only)
    float cu = ((float)(bx * 8) + 3.5f - 63.5f) / FOCAL;
    float cv = ((float)(by * 8) + 3.5f - 63.5f) / FOCAL;
    const float hw = 3.5f / FOCAL;

    // ---- cull phase: wave handles gaussians [wave*128, wave*128+128) ----
    int g0 = wave * 128 + lane;
    float4 bb0 = sbbox[g0];
    float4 bb1 = sbbox[g0 + 64];
    bool p0 = (fabsf(bb0.x - cu) <= bb0.z + hw) && (fabsf(bb0.y - cv) <= bb0.w + hw);
    bool p1 = (fabsf(bb1.x - cu) <= bb1.z + hw) && (fabsf(bb1.y - cv) <= bb1.w + hw);
    unsigned long long m0 = __ballot(p0);
    unsigned long long m1 = __ballot(p1);
    int n0 = __popcll(m0);
    int n1 = __popcll(m1);
    if (lane == 0) wcnt[wave] = n0 + n1;
    __syncthreads();

    int base = 0, Ltot = 0;
    #pragma unroll
    for (int w = 0; w < NSEG; ++w) {
        int c = wcnt[w];
        if (w < wave) base += c;
        Ltot += c;
    }
    unsigned long long lanemask = (1ull << lane) - 1ull;
    if (p0) list[base + __popcll(m0 & lanemask)] = (unsigned short)g0;
    if (p1) list[base + n0 + __popcll(m1 & lanemask)] = (unsigned short)(g0 + 64);
    __syncthreads();

    // ---- composite phase ----
    int px = bx * 8 + (lane & 7);
    int py = by * 8 + (lane >> 3);
    float gu = ((float)px - 63.5f) / FOCAL;
    float gv = ((float)py - 63.5f) / FOCAL;

    int s = (Ltot * wave) >> 4;
    int e = (Ltot * (wave + 1)) >> 4;

    float T = 1.0f, cr = 0.0f, cg = 0.0f, cb = 0.0f;

    for (int i = s; i < e; ++i) {
        int idx = __builtin_amdgcn_readfirstlane((int)list[i]);
        const float4* __restrict__ sp = sorted + (size_t)idx * 3;
        float4 q0 = sp[0];  // u, v, A, B
        float4 q1 = sp[1];  // C, osig, r, g
        float4 q2 = sp[2];  // b, -, -, -

        float dx = gu - q0.x;
        float dy = gv - q0.y;
        float t1 = fmaf(q0.w, dy, q0.z * dx);
        float p  = fmaf(t1, dx, q1.x * (dy * dy));
        p = fminf(p, 0.0f);
        float gw = EXP2F(p);
        float alpha = fminf(q1.y * gw, 0.99f);
        float w = alpha * T;
        cr = fmaf(w, q1.z, cr);
        cg = fmaf(w, q1.w, cg);
        cb = fmaf(w, q2.x, cb);
        T = fmaf(-alpha, T, T);
    }

    seg[wave][lane] = make_float4(cr, cg, cb, T);
    __syncthreads();

    if (t < 64) {
        float Tt = 1.0f, r = 0.0f, g = 0.0f, b = 0.0f;
        #pragma unroll
        for (int sgi = 0; sgi < NSEG; ++sgi) {
            float4 v = seg[sgi][t];
            r = fmaf(Tt, v.x, r);
            g = fmaf(Tt, v.y, g);
            b = fmaf(Tt, v.z, b);
            Tt *= v.w;
        }
        int p = py * WW + px;
        out[p * 3 + 0] = r;
        out[p * 3 + 1] = g;
        out[p * 3 + 2] = b;
    }
}

extern "C" void kernel_launch(void* const* d_in, const int* in_sizes, int n_in,
                              void* d_out, int out_size, void* d_ws, size_t ws_size,
                              hipStream_t stream) {
    const float* pos   = (const float*)d_in[0];
    const float* rgb   = (const float*)d_in[1];
    const float* opa   = (const float*)d_in[2];
    const float* quat  = (const float*)d_in[3];
    const float* scale = (const float*)d_in[4];
    const float* w2c   = (const float*)d_in[5];
    const float* tran  = (const float*)d_in[6];
    float* out = (float*)d_out;

    char* ws = (char*)d_ws;
    float4* params = (float4*)(ws + WS_PARAMS_OFF);
    float4* bbox   = (float4*)(ws + WS_BBOX_OFF);
    unsigned long long* keys = (unsigned long long*)(ws + WS_KEYS_OFF);
    float4* sorted = (float4*)(ws + WS_SORTED_OFF);
    float4* sbbox  = (float4*)(ws + WS_SBBOX_OFF);

    splat_preprocess<<<(NG + 255) / 256, 256, 0, stream>>>(pos, rgb, opa, quat, scale, w2c, tran,
                                                           params, bbox, keys);
    splat_rank_scatter<<<NG / 64, 1024, 0, stream>>>(keys, params, bbox, sorted, sbbox);
    splat_render<<<(HH * WW) / 64, 1024, 0, stream>>>(sbbox, sorted, out);
}

// Round 5
// 14.581 us; speedup vs baseline: 42.8180x; 1.3387x over previous
//
#include <hip/hip_runtime.h>
#include <math.h>

#define NG 2048
#define HH 128
#define WW 128
#define FOCAL 110.0f
#define NEARP 0.3f
#define EPSS 1e-4f
#define LOWPASS (0.3f / (110.0f * 110.0f))
#define L2E 1.4426950408889634f
#define LN_INV_ACUT 11.512925465f   // ln(1e5): alpha cutoff 1e-5

#define NSEG 16
#define CAP 640                      // params chunk capacity (LDS-limited)

#if defined(__has_builtin) && __has_builtin(__builtin_amdgcn_exp2f)
#define EXP2F(x) __builtin_amdgcn_exp2f(x)
#else
#define EXP2F(x) exp2f(x)
#endif

struct Proj {
    float u, v, a, b, c, z, osig;
    bool valid;
};

// Full projection + 2D covariance for one gaussian.
__device__ __forceinline__ Proj project_one(int g,
        const float* __restrict__ pos, const float* __restrict__ opa,
        const float* __restrict__ quat, const float* __restrict__ scale,
        const float* __restrict__ w2c, const float* __restrict__ tran) {
    float W00 = w2c[0], W01 = w2c[1], W02 = w2c[2];
    float W10 = w2c[3], W11 = w2c[4], W12 = w2c[5];
    float W20 = w2c[6], W21 = w2c[7], W22 = w2c[8];

    float px = pos[g * 3 + 0], py = pos[g * 3 + 1], pz = pos[g * 3 + 2];
    float cx = W00 * px + W01 * py + W02 * pz + tran[0];
    float cy = W10 * px + W11 * py + W12 * pz + tran[1];
    float cz = W20 * px + W21 * py + W22 * pz + tran[2];

    bool valid = cz > NEARP;
    float zs = valid ? cz : 1.0f;
    float u = cx / zs;
    float v = cy / zs;

    float qw = quat[g * 4 + 0], qx = quat[g * 4 + 1], qy = quat[g * 4 + 2], qz = quat[g * 4 + 3];
    float qn = sqrtf(qw * qw + qx * qx + qy * qy + qz * qz) + 1e-8f;
    float inv = 1.0f / qn;
    qw *= inv; qx *= inv; qy *= inv; qz *= inv;
    float R00 = 1.0f - 2.0f * (qy * qy + qz * qz);
    float R01 = 2.0f * (qx * qy - qw * qz);
    float R02 = 2.0f * (qx * qz + qw * qy);
    float R10 = 2.0f * (qx * qy + qw * qz);
    float R11 = 1.0f - 2.0f * (qx * qx + qz * qz);
    float R12 = 2.0f * (qy * qz - qw * qx);
    float R20 = 2.0f * (qx * qz - qw * qy);
    float R21 = 2.0f * (qy * qz + qw * qx);
    float R22 = 1.0f - 2.0f * (qx * qx + qy * qy);

    float s0 = fabsf(scale[g * 3 + 0]) + EPSS;
    float s1 = fabsf(scale[g * 3 + 1]) + EPSS;
    float s2 = fabsf(scale[g * 3 + 2]) + EPSS;

    float A00 = R00 * s0, A01 = R01 * s1, A02 = R02 * s2;
    float A10 = R10 * s0, A11 = R11 * s1, A12 = R12 * s2;
    float A20 = R20 * s0, A21 = R21 * s1, A22 = R22 * s2;
    float C00 = A00 * A00 + A01 * A01 + A02 * A02;
    float C01 = A00 * A10 + A01 * A11 + A02 * A12;
    float C02 = A00 * A20 + A01 * A21 + A02 * A22;
    float C11 = A10 * A10 + A11 * A11 + A12 * A12;
    float C12 = A10 * A20 + A11 * A21 + A12 * A22;
    float C22 = A20 * A20 + A21 * A21 + A22 * A22;

    float B00 = W00 * C00 + W01 * C01 + W02 * C02;
    float B01 = W00 * C01 + W01 * C11 + W02 * C12;
    float B02 = W00 * C02 + W01 * C12 + W02 * C22;
    float B10 = W10 * C00 + W11 * C01 + W12 * C02;
    float B11 = W10 * C01 + W11 * C11 + W12 * C12;
    float B12 = W10 * C02 + W11 * C12 + W12 * C22;
    float B20 = W20 * C00 + W21 * C01 + W22 * C02;
    float B21 = W20 * C01 + W21 * C11 + W22 * C12;
    float B22 = W20 * C02 + W21 * C12 + W22 * C22;
    float M00 = B00 * W00 + B01 * W01 + B02 * W02;
    float M01 = B00 * W10 + B01 * W11 + B02 * W12;
    float M02 = B00 * W20 + B01 * W21 + B02 * W22;
    float M11 = B10 * W10 + B11 * W11 + B12 * W12;
    float M12 = B10 * W20 + B11 * W21 + B12 * W22;
    float M22 = B20 * W20 + B21 * W21 + B22 * W22;

    float iz = 1.0f / zs;
    float iz2 = iz * iz;
    Proj r;
    r.a = iz2 * (M00 - 2.0f * u * M02 + u * u * M22) + LOWPASS;
    r.b = iz2 * (M01 - v * M02 - u * M12 + u * v * M22);
    r.c = iz2 * (M11 - 2.0f * v * M12 + v * v * M22) + LOWPASS;
    r.u = u; r.v = v; r.z = cz; r.valid = valid;
    r.osig = valid ? (1.0f / (1.0f + expf(-opa[g]))) : 0.0f;
    return r;
}

// One block per 8x8 tile: cull -> rank-sort -> preprocess survivors -> composite.
__global__ __launch_bounds__(1024) void splat_fused(const float* __restrict__ pos,
                                                    const float* __restrict__ rgb,
                                                    const float* __restrict__ opa,
                                                    const float* __restrict__ quat,
                                                    const float* __restrict__ scale,
                                                    const float* __restrict__ w2c,
                                                    const float* __restrict__ tran,
                                                    float* __restrict__ out) {
    __shared__ unsigned long long zk[NG];   // survivor keys (compact, unsorted)  16 KB
    __shared__ unsigned short srt[NG];      // survivor gaussian ids, depth order  4 KB
    __shared__ float4 pp[CAP][3];           // survivor params chunk              30 KB
    __shared__ float4 seg[NSEG][64];        //                                     4 KB
    __shared__ float4 run[64];              // running per-pixel {C, T}            1 KB
    __shared__ int cnt;

    int t = threadIdx.x;
    int lane = t & 63;
    int wave = t >> 6;
    int bx = blockIdx.x & 15, by = blockIdx.x >> 4;

    float cu = ((float)(bx * 8) + 3.5f - 63.5f) / FOCAL;
    float cv = ((float)(by * 8) + 3.5f - 63.5f) / FOCAL;
    const float hw = 3.5f / FOCAL;

    if (t == 0) cnt = 0;
    if (t < 64) run[t] = make_float4(0.0f, 0.0f, 0.0f, 1.0f);
    __syncthreads();

    // ---- phase 1: project + cull (2 gaussians/thread); compact keys ----
    #pragma unroll
    for (int part = 0; part < 2; ++part) {
        int g = t + part * 1024;
        Proj P = project_one(g, pos, opa, quat, scale, w2c, tran);
        float tau = 2.0f * (logf(P.osig) + LN_INV_ACUT);   // osig=0 -> -inf
        bool survive = false;
        if (P.valid && tau > 0.0f) {
            float ru = sqrtf(tau * P.a);
            float rv = sqrtf(tau * P.c);
            survive = (fabsf(P.u - cu) <= ru + hw) && (fabsf(P.v - cv) <= rv + hw);
        }
        if (survive) {
            int s = atomicAdd(&cnt, 1);
            zk[s] = ((unsigned long long)__float_as_uint(P.z) << 32) | (unsigned int)g;
        }
    }
    __syncthreads();
    int L = cnt;

    // ---- phase 2: rank sort survivors by (z, idx) — keys unique ----
    for (int i = t; i < L; i += 1024) {
        unsigned long long ki = zk[i];
        int r = 0;
        #pragma unroll 4
        for (int j = 0; j < L; ++j) r += (zk[j] < ki) ? 1 : 0;
        srt[r] = (unsigned short)(ki & 0xffffu);
    }
    __syncthreads();

    // ---- chunked: preprocess survivors into LDS, composite in depth order ----
    int px = bx * 8 + (lane & 7);
    int py = by * 8 + (lane >> 3);
    float gu = ((float)px - 63.5f) / FOCAL;
    float gv = ((float)py - 63.5f) / FOCAL;

    for (int off = 0; off < L; off += CAP) {
        int CL = min(CAP, L - off);

        // phase 3: full params for this chunk (one survivor per thread)
        if (t < CL) {
            int g = srt[off + t];
            Proj P = project_one(g, pos, opa, quat, scale, w2c, tran);
            float det = fmaxf(P.a * P.c - P.b * P.b, 1e-12f);
            float idet = 1.0f / det;
            float Af = -0.5f * L2E * (P.c * idet);
            float Bf =  L2E * (P.b * idet);          // -L2E * ib, ib = -b*idet
            float Cf = -0.5f * L2E * (P.a * idet);
            float rr = 1.0f / (1.0f + expf(-rgb[g * 3 + 0]));
            float gg = 1.0f / (1.0f + expf(-rgb[g * 3 + 1]));
            float bb = 1.0f / (1.0f + expf(-rgb[g * 3 + 2]));
            pp[t][0] = make_float4(P.u, P.v, Af, Bf);
            pp[t][1] = make_float4(Cf, P.osig, rr, gg);
            pp[t][2] = make_float4(bb, 0.0f, 0.0f, 0.0f);
        }
        __syncthreads();

        // phase 4: segmented composite over the chunk
        int s = (CL * wave) >> 4;
        int e = (CL * (wave + 1)) >> 4;
        float T = 1.0f, cr = 0.0f, cg = 0.0f, cb = 0.0f;
        for (int i = s; i < e; ++i) {
            float4 q0 = pp[i][0];  // u, v, A, B
            float4 q1 = pp[i][1];  // C, osig, r, g
            float4 q2 = pp[i][2];  // b

            float dx = gu - q0.x;
            float dy = gv - q0.y;
            float t1 = fmaf(q0.w, dy, q0.z * dx);
            float p  = fmaf(t1, dx, q1.x * (dy * dy));
            p = fminf(p, 0.0f);
            float gw = EXP2F(p);
            float alpha = fminf(q1.y * gw, 0.99f);
            float w = alpha * T;
            cr = fmaf(w, q1.z, cr);
            cg = fmaf(w, q1.w, cg);
            cb = fmaf(w, q2.x, cb);
            T = fmaf(-alpha, T, T);
        }
        seg[wave][lane] = make_float4(cr, cg, cb, T);
        __syncthreads();

        // ordered combine of 16 segments, fold into running state
        if (t < 64) {
            float Tt = 1.0f, r = 0.0f, g = 0.0f, b = 0.0f;
            #pragma unroll
            for (int sgi = 0; sgi < NSEG; ++sgi) {
                float4 v = seg[sgi][t];
                r = fmaf(Tt, v.x, r);
                g = fmaf(Tt, v.y, g);
                b = fmaf(Tt, v.z, b);
                Tt *= v.w;
            }
            float4 R = run[t];
            run[t] = make_float4(fmaf(R.w, r, R.x), fmaf(R.w, g, R.y),
                                 fmaf(R.w, b, R.z), R.w * Tt);
        }
        __syncthreads();
    }

    if (t < 64) {
        float4 R = run[t];
        int p = py * WW + px;
        out[p * 3 + 0] = R.x;
        out[p * 3 + 1] = R.y;
        out[p * 3 + 2] = R.z;
    }
}

extern "C" void kernel_launch(void* const* d_in, const int* in_sizes, int n_in,
                              void* d_out, int out_size, void* d_ws, size_t ws_size,
                              hipStream_t stream) {
    const float* pos   = (const float*)d_in[0];
    const float* rgb   = (const float*)d_in[1];
    const float* opa   = (const float*)d_in[2];
    const float* quat  = (const float*)d_in[3];
    const float* scale = (const float*)d_in[4];
    const float* w2c   = (const float*)d_in[5];
    const float* tran  = (const float*)d_in[6];
    float* out = (float*)d_out;

    splat_fused<<<(HH * WW) / 64, 1024, 0, stream>>>(pos, rgb, opa, quat, scale, w2c, tran, out);
}

// Round 6
// 12.643 us; speedup vs baseline: 49.3825x; 1.1533x over previous
//
#include <hip/hip_runtime.h>
#include <hip/hip_fp16.h>
#include <math.h>

#define NG 2048
#define HH 128
#define WW 128
#define FOCAL 110.0f
#define NEARP 0.3f
#define EPSS 1e-4f
#define LOWPASS (0.3f / (110.0f * 110.0f))
#define L2E 1.4426950408889634f
#define INV_L2E 0.6931471805599453f
#define LN_INV_ACUT 11.512925465f   // ln(1e5): alpha cutoff 1e-5

#define NSEG 16

// fast native f32 ops (error ~1e-5 rel; threshold is 1.6e-2, current absmax 2e-3)
#define EXP2F(x) __builtin_amdgcn_exp2f(x)
#define LOG2F(x) __builtin_amdgcn_logf(x)
#define RCPF(x)  __builtin_amdgcn_rcpf(x)
#define SQRTF(x) __builtin_amdgcn_sqrtf(x)

struct Proj {
    float u, v, a, b, c, z, osig;
    bool valid;
};

// Full projection + 2D covariance for one gaussian (fast-math variant).
// P.b is dead in the cull phase -> DCE'd there (forceinline).
__device__ __forceinline__ Proj project_one(int g,
        const float* __restrict__ pos, const float* __restrict__ opa,
        const float* __restrict__ quat, const float* __restrict__ scale,
        const float* __restrict__ w2c, const float* __restrict__ tran) {
    float W00 = w2c[0], W01 = w2c[1], W02 = w2c[2];
    float W10 = w2c[3], W11 = w2c[4], W12 = w2c[5];
    float W20 = w2c[6], W21 = w2c[7], W22 = w2c[8];

    float px = pos[g * 3 + 0], py = pos[g * 3 + 1], pz = pos[g * 3 + 2];
    float cx = W00 * px + W01 * py + W02 * pz + tran[0];
    float cy = W10 * px + W11 * py + W12 * pz + tran[1];
    float cz = W20 * px + W21 * py + W22 * pz + tran[2];

    bool valid = cz > NEARP;
    float iz = valid ? RCPF(cz) : 1.0f;
    float u = cx * iz;
    float v = cy * iz;

    float qw = quat[g * 4 + 0], qx = quat[g * 4 + 1], qy = quat[g * 4 + 2], qz = quat[g * 4 + 3];
    float qq = qw * qw + qx * qx + qy * qy + qz * qz;
    float inv = RCPF(SQRTF(qq) + 1e-8f);
    qw *= inv; qx *= inv; qy *= inv; qz *= inv;
    float R00 = 1.0f - 2.0f * (qy * qy + qz * qz);
    float R01 = 2.0f * (qx * qy - qw * qz);
    float R02 = 2.0f * (qx * qz + qw * qy);
    float R10 = 2.0f * (qx * qy + qw * qz);
    float R11 = 1.0f - 2.0f * (qx * qx + qz * qz);
    float R12 = 2.0f * (qy * qz - qw * qx);
    float R20 = 2.0f * (qx * qz - qw * qy);
    float R21 = 2.0f * (qy * qz + qw * qx);
    float R22 = 1.0f - 2.0f * (qx * qx + qy * qy);

    float s0 = fabsf(scale[g * 3 + 0]) + EPSS;
    float s1 = fabsf(scale[g * 3 + 1]) + EPSS;
    float s2 = fabsf(scale[g * 3 + 2]) + EPSS;

    float A00 = R00 * s0, A01 = R01 * s1, A02 = R02 * s2;
    float A10 = R10 * s0, A11 = R11 * s1, A12 = R12 * s2;
    float A20 = R20 * s0, A21 = R21 * s1, A22 = R22 * s2;
    float C00 = A00 * A00 + A01 * A01 + A02 * A02;
    float C01 = A00 * A10 + A01 * A11 + A02 * A12;
    float C02 = A00 * A20 + A01 * A21 + A02 * A22;
    float C11 = A10 * A10 + A11 * A11 + A12 * A12;
    float C12 = A10 * A20 + A11 * A21 + A12 * A22;
    float C22 = A20 * A20 + A21 * A21 + A22 * A22;

    float B00 = W00 * C00 + W01 * C01 + W02 * C02;
    float B01 = W00 * C01 + W01 * C11 + W02 * C12;
    float B02 = W00 * C02 + W01 * C12 + W02 * C22;
    float B10 = W10 * C00 + W11 * C01 + W12 * C02;
    float B11 = W10 * C01 + W11 * C11 + W12 * C12;
    float B12 = W10 * C02 + W11 * C12 + W12 * C22;
    float B20 = W20 * C00 + W21 * C01 + W22 * C02;
    float B21 = W20 * C01 + W21 * C11 + W22 * C12;
    float B22 = W20 * C02 + W21 * C12 + W22 * C22;
    float M00 = B00 * W00 + B01 * W01 + B02 * W02;
    float M01 = B00 * W10 + B01 * W11 + B02 * W12;
    float M02 = B00 * W20 + B01 * W21 + B02 * W22;
    float M11 = B10 * W10 + B11 * W11 + B12 * W12;
    float M12 = B10 * W20 + B11 * W21 + B12 * W22;
    float M22 = B20 * W20 + B21 * W21 + B22 * W22;

    float iz2 = iz * iz;
    Proj r;
    r.a = iz2 * (M00 - 2.0f * u * M02 + u * u * M22) + LOWPASS;
    r.b = iz2 * (M01 - v * M02 - u * M12 + u * v * M22);
    r.c = iz2 * (M11 - 2.0f * v * M12 + v * v * M22) + LOWPASS;
    r.u = u; r.v = v; r.z = cz; r.valid = valid;
    // sigmoid via native exp2; e reused for tau in the cull phase
    float e = EXP2F(-opa[g] * L2E);
    r.osig = valid ? RCPF(1.0f + e) : 0.0f;
    return r;
}

__device__ __forceinline__ float fast_sigmoid(float x) {
    return RCPF(1.0f + EXP2F(-x * L2E));
}

// One block per 8x8 tile: cull -> rank-sort -> preprocess survivors -> composite.
__global__ __launch_bounds__(1024) void splat_fused(const float* __restrict__ pos,
                                                    const float* __restrict__ rgb,
                                                    const float* __restrict__ opa,
                                                    const float* __restrict__ quat,
                                                    const float* __restrict__ scale,
                                                    const float* __restrict__ w2c,
                                                    const float* __restrict__ tran,
                                                    float* __restrict__ out) {
    __shared__ unsigned long long zk[NG];   // survivor keys (compact, unsorted)  16 KB
    __shared__ unsigned short srt[NG];      // survivor ids, depth order           4 KB
    __shared__ float4 ppA[NG];              // {u,v,Af,Bf}                        32 KB
    __shared__ float4 ppB[NG];              // {Cf,osig,half2(r,g),half2(b,0)}    32 KB
    __shared__ float4 seg[NSEG][64];        //                                     4 KB
    __shared__ int cnt;

    int t = threadIdx.x;
    int lane = t & 63;
    int wave = t >> 6;
    int bx = blockIdx.x & 15, by = blockIdx.x >> 4;

    float cu = ((float)(bx * 8) + 3.5f - 63.5f) / FOCAL;
    float cv = ((float)(by * 8) + 3.5f - 63.5f) / FOCAL;
    const float hw = 3.5f / FOCAL;

    if (t == 0) cnt = 0;
    __syncthreads();

    // ---- phase 1: project + cull (2 gaussians/thread); compact keys ----
    #pragma unroll
    for (int part = 0; part < 2; ++part) {
        int g = t + part * 1024;
        Proj P = project_one(g, pos, opa, quat, scale, w2c, tran);
        // tau = 2*(ln(osig) + ln(1e5)); ln(osig) = -log2(1+e^-o)/log2(e)
        float e = EXP2F(-opa[g] * L2E);
        float tau = 2.0f * (LN_INV_ACUT - LOG2F(1.0f + e) * INV_L2E);
        bool survive = false;
        if (P.valid && tau > 0.0f) {
            float ru = SQRTF(tau * P.a);
            float rv = SQRTF(tau * P.c);
            survive = (fabsf(P.u - cu) <= ru + hw) && (fabsf(P.v - cv) <= rv + hw);
        }
        if (survive) {
            int s = atomicAdd(&cnt, 1);
            zk[s] = ((unsigned long long)__float_as_uint(P.z) << 32) | (unsigned int)g;
        }
    }
    __syncthreads();
    int L = cnt;

    // ---- phase 2: rank sort survivors by (z, idx) — keys unique ----
    for (int i = t; i < L; i += 1024) {
        unsigned long long ki = zk[i];
        int r = 0;
        #pragma unroll 4
        for (int j = 0; j < L; ++j) r += (zk[j] < ki) ? 1 : 0;
        srt[r] = (unsigned short)(ki & 0xffffu);
    }
    __syncthreads();

    // ---- phase 3: full params for survivors (packed, 32 B each) ----
    for (int i = t; i < L; i += 1024) {
        int g = srt[i];
        Proj P = project_one(g, pos, opa, quat, scale, w2c, tran);
        float det = fmaxf(P.a * P.c - P.b * P.b, 1e-12f);
        float idet = RCPF(det);
        float Af = -0.5f * L2E * (P.c * idet);
        float Bf =  L2E * (P.b * idet);
        float Cf = -0.5f * L2E * (P.a * idet);
        float rr = fast_sigmoid(rgb[g * 3 + 0]);
        float gg = fast_sigmoid(rgb[g * 3 + 1]);
        float bb = fast_sigmoid(rgb[g * 3 + 2]);
        union { __half2 h; float f; } prg, pb;
        prg.h = __floats2half2_rn(rr, gg);
        pb.h  = __floats2half2_rn(bb, 0.0f);
        ppA[i] = make_float4(P.u, P.v, Af, Bf);
        ppB[i] = make_float4(Cf, P.osig, prg.f, pb.f);
    }
    __syncthreads();

    // ---- phase 4: segmented composite ----
    int px = bx * 8 + (lane & 7);
    int py = by * 8 + (lane >> 3);
    float gu = ((float)px - 63.5f) / FOCAL;
    float gv = ((float)py - 63.5f) / FOCAL;

    int s = (L * wave) >> 4;
    int e = (L * (wave + 1)) >> 4;

    float T = 1.0f, cr = 0.0f, cg = 0.0f, cb = 0.0f;
    for (int i = s; i < e; ++i) {
        float4 q0 = ppA[i];
        float4 q1 = ppB[i];

        float dx = gu - q0.x;
        float dy = gv - q0.y;
        float t1 = fmaf(q0.w, dy, q0.z * dx);
        float p  = fmaf(t1, dx, q1.x * (dy * dy));
        p = fminf(p, 0.0f);
        float gw = EXP2F(p);
        float alpha = fminf(q1.y * gw, 0.99f);
        float w = alpha * T;

        union { float f; __half2 h; } crg, cbb;
        crg.f = q1.z; cbb.f = q1.w;
        float2 rg = __half22float2(crg.h);
        float bch = __low2float(cbb.h);

        cr = fmaf(w, rg.x, cr);
        cg = fmaf(w, rg.y, cg);
        cb = fmaf(w, bch, cb);
        T = fmaf(-alpha, T, T);
    }
    seg[wave][lane] = make_float4(cr, cg, cb, T);
    __syncthreads();

    // ordered combine of 16 segments -> output
    if (t < 64) {
        float Tt = 1.0f, r = 0.0f, g = 0.0f, b = 0.0f;
        #pragma unroll
        for (int sgi = 0; sgi < NSEG; ++sgi) {
            float4 v = seg[sgi][t];
            r = fmaf(Tt, v.x, r);
            g = fmaf(Tt, v.y, g);
            b = fmaf(Tt, v.z, b);
            Tt *= v.w;
        }
        int p = py * WW + px;
        out[p * 3 + 0] = r;
        out[p * 3 + 1] = g;
        out[p * 3 + 2] = b;
    }
}

extern "C" void kernel_launch(void* const* d_in, const int* in_sizes, int n_in,
                              void* d_out, int out_size, void* d_ws, size_t ws_size,
                              hipStream_t stream) {
    const float* pos   = (const float*)d_in[0];
    const float* rgb   = (const float*)d_in[1];
    const float* opa   = (const float*)d_in[2];
    const float* quat  = (const float*)d_in[3];
    const float* scale = (const float*)d_in[4];
    const float* w2c   = (const float*)d_in[5];
    const float* tran  = (const float*)d_in[6];
    float* out = (float*)d_out;

    splat_fused<<<(HH * WW) / 64, 1024, 0, stream>>>(pos, rgb, opa, quat, scale, w2c, tran, out);
}

// Round 7
// 11.296 us; speedup vs baseline: 55.2686x; 1.1192x over previous
//
#include <hip/hip_runtime.h>
#include <hip/hip_fp16.h>
#include <math.h>

#define NG 2048
#define HH 128
#define WW 128
#define FOCAL 110.0f
#define NEARP 0.3f
#define EPSS 1e-4f
#define LOWPASS (0.3f / (110.0f * 110.0f))
#define L2E 1.4426950408889634f
#define INV_L2E 0.6931471805599453f
#define LN_INV_ACUT 11.512925465f   // ln(1e5): alpha cutoff 1e-5

#define NSEG 16

// fast native f32 ops (error ~1e-5 rel; threshold 1.6e-2, current absmax 3.9e-3)
#define EXP2F(x) __builtin_amdgcn_exp2f(x)
#define LOG2F(x) __builtin_amdgcn_logf(x)
#define RCPF(x)  __builtin_amdgcn_rcpf(x)

__device__ __forceinline__ float fast_sigmoid(float x) {
    return RCPF(1.0f + EXP2F(-x * L2E));
}

// One block per 8x8 tile: project+cull (G-form) -> parallel rank-sort ->
// rgb fill -> composite via rank->slot indirection.
__global__ __launch_bounds__(1024) void splat_fused(const float* __restrict__ pos,
                                                    const float* __restrict__ rgb,
                                                    const float* __restrict__ opa,
                                                    const float4* __restrict__ quat,
                                                    const float* __restrict__ scale,
                                                    const float* __restrict__ w2c,
                                                    const float* __restrict__ tran,
                                                    float* __restrict__ out) {
    __shared__ unsigned long long zk[NG];   // survivor keys by slot             16 KB
    __shared__ float4 ppA[NG];              // {u,v,Af,Bf} by slot               32 KB
    __shared__ float4 ppB[NG];              // {Cf,osig,h2(r,g),h2(b,0)} by slot 32 KB
    __shared__ unsigned short srt[NG];      // rank -> slot                       4 KB
    __shared__ float4 seg[NSEG][64];        //                                    4 KB
    __shared__ int cnt;

    int t = threadIdx.x;
    int lane = t & 63;
    int wave = t >> 6;
    int bx = blockIdx.x & 15, by = blockIdx.x >> 4;

    float cu = ((float)(bx * 8) + 3.5f - 63.5f) / FOCAL;
    float cv = ((float)(by * 8) + 3.5f - 63.5f) / FOCAL;
    const float hw = 3.5f / FOCAL;

    if (t == 0) cnt = 0;
    __syncthreads();

    // uniform camera (scalar loads)
    float W00 = w2c[0], W01 = w2c[1], W02 = w2c[2];
    float W10 = w2c[3], W11 = w2c[4], W12 = w2c[5];
    float W20 = w2c[6], W21 = w2c[7], W22 = w2c[8];
    float t0 = tran[0], t1 = tran[1], t2 = tran[2];

    // ---- phase 1: project + cull (2 gaussians/thread); finish conic on survive ----
    #pragma unroll
    for (int part = 0; part < 2; ++part) {
        int g = t + part * 1024;

        float px = pos[g * 3 + 0], py = pos[g * 3 + 1], pz = pos[g * 3 + 2];
        float cx = W00 * px + W01 * py + W02 * pz + t0;
        float cy = W10 * px + W11 * py + W12 * pz + t1;
        float cz = W20 * px + W21 * py + W22 * pz + t2;

        bool valid = cz > NEARP;
        float iz = valid ? RCPF(cz) : 1.0f;
        float u = cx * iz;
        float v = cy * iz;

        // opacity -> sigmoid + tau = 2*(ln(osig)+ln(1e5)) ; ln(osig) = -log2(1+e)*ln2
        float e = EXP2F(-opa[g] * L2E);
        float osig = RCPF(1.0f + e);
        float tau = 2.0f * (LN_INV_ACUT - LOG2F(1.0f + e) * INV_L2E);

        // K = J*W rows (2x3)
        float k00 = iz * (W00 - u * W20), k01 = iz * (W01 - u * W21), k02 = iz * (W02 - u * W22);
        float k10 = iz * (W10 - v * W20), k11 = iz * (W11 - v * W21), k12 = iz * (W12 - v * W22);

        // quat -> R
        float4 q = quat[g];
        float qw = q.x, qx = q.y, qy = q.z, qz = q.w;
        float qq = qw * qw + qx * qx + qy * qy + qz * qz;
        float inv = RCPF(__builtin_amdgcn_sqrtf(qq) + 1e-8f);
        qw *= inv; qx *= inv; qy *= inv; qz *= inv;
        float R00 = 1.0f - 2.0f * (qy * qy + qz * qz);
        float R01 = 2.0f * (qx * qy - qw * qz);
        float R02 = 2.0f * (qx * qz + qw * qy);
        float R10 = 2.0f * (qx * qy + qw * qz);
        float R11 = 1.0f - 2.0f * (qx * qx + qz * qz);
        float R12 = 2.0f * (qy * qz - qw * qx);
        float R20 = 2.0f * (qx * qz - qw * qy);
        float R21 = 2.0f * (qy * qz + qw * qx);
        float R22 = 1.0f - 2.0f * (qx * qx + qy * qy);

        float s0 = fabsf(scale[g * 3 + 0]) + EPSS;
        float s1 = fabsf(scale[g * 3 + 1]) + EPSS;
        float s2 = fabsf(scale[g * 3 + 2]) + EPSS;

        // G = K * R * diag(s)  (2x3); cov2 = G G^T
        float g00 = (k00 * R00 + k01 * R10 + k02 * R20) * s0;
        float g01 = (k00 * R01 + k01 * R11 + k02 * R21) * s1;
        float g02 = (k00 * R02 + k01 * R12 + k02 * R22) * s2;
        float g10 = (k10 * R00 + k11 * R10 + k12 * R20) * s0;
        float g11 = (k10 * R01 + k11 * R11 + k12 * R21) * s1;
        float g12 = (k10 * R02 + k11 * R12 + k12 * R22) * s2;

        float a = g00 * g00 + g01 * g01 + g02 * g02 + LOWPASS;
        float c = g10 * g10 + g11 * g11 + g12 * g12 + LOWPASS;

        // squared-compare cull: max(|du|-hw,0)^2 <= tau*a
        float du = fmaxf(fabsf(u - cu) - hw, 0.0f);
        float dv = fmaxf(fabsf(v - cv) - hw, 0.0f);
        bool survive = valid && (tau > 0.0f) &&
                       (du * du <= tau * a) && (dv * dv <= tau * c);

        if (survive) {
            float b = g00 * g10 + g01 * g11 + g02 * g12;
            float det = fmaxf(a * c - b * b, 1e-12f);
            float idet = RCPF(det);
            float Af = -0.5f * L2E * (c * idet);
            float Bf =  L2E * (b * idet);
            float Cf = -0.5f * L2E * (a * idet);
            int s = atomicAdd(&cnt, 1);
            zk[s] = ((unsigned long long)__float_as_uint(cz) << 32) | (unsigned int)g;
            ppA[s] = make_float4(u, v, Af, Bf);
            ppB[s] = make_float4(Cf, osig, 0.0f, 0.0f);
        }
    }
    __syncthreads();
    int L = cnt;

    // ---- phase 2: parallel rank sort (16 threads/item, shfl-reduce) ----
    {
        int sub = t & 15;
        for (int i = t >> 4; i < L; i += 64) {
            unsigned long long ki = zk[i];
            int r = 0;
            for (int j = sub; j < L; j += 16) r += (zk[j] < ki) ? 1 : 0;
            r += __shfl_xor(r, 1);
            r += __shfl_xor(r, 2);
            r += __shfl_xor(r, 4);
            r += __shfl_xor(r, 8);
            if (sub == 0) srt[r] = (unsigned short)i;
        }
    }

    // ---- phase 3: rgb sigmoids for survivors (slot order) ----
    for (int i = t; i < L; i += 1024) {
        int g = (int)(zk[i] & 0xffffu);
        float rr = fast_sigmoid(rgb[g * 3 + 0]);
        float gg = fast_sigmoid(rgb[g * 3 + 1]);
        float bb = fast_sigmoid(rgb[g * 3 + 2]);
        union { __half2 h; float f; } prg, pb;
        prg.h = __floats2half2_rn(rr, gg);
        pb.h  = __floats2half2_rn(bb, 0.0f);
        ppB[i].z = prg.f;
        ppB[i].w = pb.f;
    }
    __syncthreads();

    // ---- phase 4: segmented composite via rank->slot indirection ----
    int px = bx * 8 + (lane & 7);
    int py = by * 8 + (lane >> 3);
    float gu = ((float)px - 63.5f) / FOCAL;
    float gv = ((float)py - 63.5f) / FOCAL;

    int s = (L * wave) >> 4;
    int e = (L * (wave + 1)) >> 4;

    float T = 1.0f, cr = 0.0f, cg = 0.0f, cb = 0.0f;
    for (int i = s; i < e; ++i) {
        int slot = srt[i];               // uniform broadcast read
        float4 q0 = ppA[slot];
        float4 q1 = ppB[slot];

        float dx = gu - q0.x;
        float dy = gv - q0.y;
        float t1v = fmaf(q0.w, dy, q0.z * dx);
        float p   = fmaf(t1v, dx, q1.x * (dy * dy));
        p = fminf(p, 0.0f);
        float gw = EXP2F(p);
        float alpha = fminf(q1.y * gw, 0.99f);
        float w = alpha * T;

        union { float f; __half2 h; } crg, cbb;
        crg.f = q1.z; cbb.f = q1.w;
        float2 rgv = __half22float2(crg.h);
        float bch = __low2float(cbb.h);

        cr = fmaf(w, rgv.x, cr);
        cg = fmaf(w, rgv.y, cg);
        cb = fmaf(w, bch, cb);
        T = fmaf(-alpha, T, T);
    }
    seg[wave][lane] = make_float4(cr, cg, cb, T);
    __syncthreads();

    // ordered combine of 16 segments -> output
    if (t < 64) {
        float Tt = 1.0f, r = 0.0f, g = 0.0f, b = 0.0f;
        #pragma unroll
        for (int sgi = 0; sgi < NSEG; ++sgi) {
            float4 v = seg[sgi][t];
            r = fmaf(Tt, v.x, r);
            g = fmaf(Tt, v.y, g);
            b = fmaf(Tt, v.z, b);
            Tt *= v.w;
        }
        int p = py * WW + px;
        out[p * 3 + 0] = r;
        out[p * 3 + 1] = g;
        out[p * 3 + 2] = b;
    }
}

extern "C" void kernel_launch(void* const* d_in, const int* in_sizes, int n_in,
                              void* d_out, int out_size, void* d_ws, size_t ws_size,
                              hipStream_t stream) {
    const float* pos   = (const float*)d_in[0];
    const float* rgb   = (const float*)d_in[1];
    const float* opa   = (const float*)d_in[2];
    const float4* quat = (const float4*)d_in[3];
    const float* scale = (const float*)d_in[4];
    const float* w2c   = (const float*)d_in[5];
    const float* tran  = (const float*)d_in[6];
    float* out = (float*)d_out;

    splat_fused<<<(HH * WW) / 64, 1024, 0, stream>>>(pos, rgb, opa, quat, scale, w2c, tran, out);
}

// Round 8
// 10.670 us; speedup vs baseline: 58.5116x; 1.0587x over previous
//
#include <hip/hip_runtime.h>
#include <hip/hip_fp16.h>
#include <math.h>

#define NG 2048
#define HH 128
#define WW 128
#define FOCAL 110.0f
#define NEARP 0.3f
#define EPSS 1e-4f
#define LOWPASS (0.3f / (110.0f * 110.0f))
#define L2E 1.4426950408889634f
#define INV_L2E 0.6931471805599453f
#define LN_INV_ACUT 11.512925465f   // ln(1e5): alpha cutoff 1e-5

#define NSEG 16

// fast native f32 ops (error ~1e-5 rel; threshold 1.6e-2, current absmax 3.9e-3)
#define EXP2F(x) __builtin_amdgcn_exp2f(x)
#define LOG2F(x) __builtin_amdgcn_logf(x)
#define RCPF(x)  __builtin_amdgcn_rcpf(x)

__device__ __forceinline__ float fast_sigmoid(float x) {
    return RCPF(1.0f + EXP2F(-x * L2E));
}

// One block per 8x8 tile.
// Phase 0: cheap exact-bound cull (no quat/cov math): a <= smax^2*iz^2*(1+u^2)
//          (w2c rows orthonormal -> |row0 of J*W|^2 = iz^2(1+u^2) exactly).
//          Candidates (~3x true survivors) compacted with (u,v,iz,osig) cached.
// Phase 1b: full conic + rgb only for candidates (masked pass, ~1/8 the volume).
// Phase 2: parallel rank sort by (z, idx).
// Phase 4: segmented composite via rank->slot indirection; ordered combine.
// False-positive candidates keep their true conic -> contribute exactly what
// the reference computes (pre-cull only drops alpha<1e-5 contributions).
__global__ __launch_bounds__(1024) void splat_fused(const float* __restrict__ pos,
                                                    const float* __restrict__ rgb,
                                                    const float* __restrict__ opa,
                                                    const float4* __restrict__ quat,
                                                    const float* __restrict__ scale,
                                                    const float* __restrict__ w2c,
                                                    const float* __restrict__ tran,
                                                    float* __restrict__ out) {
    __shared__ unsigned long long zk[NG];   // candidate keys by slot            16 KB
    __shared__ float4 ppA[NG];              // ph0: {u,v,iz,osig} -> {u,v,Af,Bf} 32 KB
    __shared__ float4 ppB[NG];              // {Cf,osig,h2(r,g),h2(b,0)}         32 KB
    __shared__ unsigned short srt[NG];      // rank -> slot                       4 KB
    __shared__ float4 seg[NSEG][64];        //                                    4 KB
    __shared__ int cnt;

    int t = threadIdx.x;
    int lane = t & 63;
    int wave = t >> 6;
    int bx = blockIdx.x & 15, by = blockIdx.x >> 4;

    float cu = ((float)(bx * 8) + 3.5f - 63.5f) / FOCAL;
    float cv = ((float)(by * 8) + 3.5f - 63.5f) / FOCAL;
    const float hw = 3.5f / FOCAL;

    if (t == 0) cnt = 0;
    __syncthreads();

    // uniform camera (scalar loads)
    float W00 = w2c[0], W01 = w2c[1], W02 = w2c[2];
    float W10 = w2c[3], W11 = w2c[4], W12 = w2c[5];
    float W20 = w2c[6], W21 = w2c[7], W22 = w2c[8];
    float t0 = tran[0], t1 = tran[1], t2 = tran[2];

    // ---- phase 0: cheap-bound cull (2 gaussians/thread), compact candidates ----
    #pragma unroll
    for (int part = 0; part < 2; ++part) {
        int g = t + part * 1024;

        float px = pos[g * 3 + 0], py = pos[g * 3 + 1], pz = pos[g * 3 + 2];
        float cx = W00 * px + W01 * py + W02 * pz + t0;
        float cy = W10 * px + W11 * py + W12 * pz + t1;
        float cz = W20 * px + W21 * py + W22 * pz + t2;

        bool valid = cz > NEARP;
        float iz = valid ? RCPF(cz) : 1.0f;
        float u = cx * iz;
        float v = cy * iz;

        // osig + tau = 2*(ln(osig)+ln(1e5));  ln(osig) = -log2(1+e)*ln2
        float e = EXP2F(-opa[g] * L2E);
        float osig = RCPF(1.0f + e);
        float tau = 2.0f * (LN_INV_ACUT - LOG2F(1.0f + e) * INV_L2E);

        float smax = fmaxf(fmaxf(fabsf(scale[g * 3 + 0]), fabsf(scale[g * 3 + 1])),
                           fabsf(scale[g * 3 + 2])) + EPSS;
        float s2iz2 = smax * smax * iz * iz * 1.0001f;
        float bound_a = fmaf(s2iz2, u * u, s2iz2) + LOWPASS;   // s2iz2*(1+u^2)+LP
        float bound_c = fmaf(s2iz2, v * v, s2iz2) + LOWPASS;

        float du = fmaxf(fabsf(u - cu) - hw, 0.0f);
        float dv = fmaxf(fabsf(v - cv) - hw, 0.0f);
        bool cand = valid && (tau > 0.0f) &&
                    (du * du <= tau * bound_a) && (dv * dv <= tau * bound_c);

        if (cand) {
            int s = atomicAdd(&cnt, 1);
            zk[s] = ((unsigned long long)__float_as_uint(cz) << 32) | (unsigned int)g;
            ppA[s] = make_float4(u, v, iz, osig);
        }
    }
    __syncthreads();
    int L = cnt;

    // ---- phase 1b: full conic + rgb for candidates (masked pass) ----
    for (int i = t; i < L; i += 1024) {
        int g = (int)(zk[i] & 0xffffu);
        float4 cach = ppA[i];
        float u = cach.x, v = cach.y, iz = cach.z, osig = cach.w;

        // K = J*W rows (2x3)
        float k00 = iz * (W00 - u * W20), k01 = iz * (W01 - u * W21), k02 = iz * (W02 - u * W22);
        float k10 = iz * (W10 - v * W20), k11 = iz * (W11 - v * W21), k12 = iz * (W12 - v * W22);

        float4 q = quat[g];
        float qw = q.x, qx = q.y, qy = q.z, qz = q.w;
        float qq = qw * qw + qx * qx + qy * qy + qz * qz;
        float inv = RCPF(__builtin_amdgcn_sqrtf(qq) + 1e-8f);
        qw *= inv; qx *= inv; qy *= inv; qz *= inv;
        float R00 = 1.0f - 2.0f * (qy * qy + qz * qz);
        float R01 = 2.0f * (qx * qy - qw * qz);
        float R02 = 2.0f * (qx * qz + qw * qy);
        float R10 = 2.0f * (qx * qy + qw * qz);
        float R11 = 1.0f - 2.0f * (qx * qx + qz * qz);
        float R12 = 2.0f * (qy * qz - qw * qx);
        float R20 = 2.0f * (qx * qz - qw * qy);
        float R21 = 2.0f * (qy * qz + qw * qx);
        float R22 = 1.0f - 2.0f * (qx * qx + qy * qy);

        float s0 = fabsf(scale[g * 3 + 0]) + EPSS;
        float s1 = fabsf(scale[g * 3 + 1]) + EPSS;
        float s2 = fabsf(scale[g * 3 + 2]) + EPSS;

        // G = K * R * diag(s)  (2x3); cov2 = G G^T
        float g00 = (k00 * R00 + k01 * R10 + k02 * R20) * s0;
        float g01 = (k00 * R01 + k01 * R11 + k02 * R21) * s1;
        float g02 = (k00 * R02 + k01 * R12 + k02 * R22) * s2;
        float g10 = (k10 * R00 + k11 * R10 + k12 * R20) * s0;
        float g11 = (k10 * R01 + k11 * R11 + k12 * R21) * s1;
        float g12 = (k10 * R02 + k11 * R12 + k12 * R22) * s2;

        float a = g00 * g00 + g01 * g01 + g02 * g02 + LOWPASS;
        float c = g10 * g10 + g11 * g11 + g12 * g12 + LOWPASS;
        float b = g00 * g10 + g01 * g11 + g02 * g12;

        float det = fmaxf(a * c - b * b, 1e-12f);
        float idet = RCPF(det);
        float Af = -0.5f * L2E * (c * idet);
        float Bf =  L2E * (b * idet);
        float Cf = -0.5f * L2E * (a * idet);

        float rr = fast_sigmoid(rgb[g * 3 + 0]);
        float gg = fast_sigmoid(rgb[g * 3 + 1]);
        float bb = fast_sigmoid(rgb[g * 3 + 2]);
        union { __half2 h; float f; } prg, pb;
        prg.h = __floats2half2_rn(rr, gg);
        pb.h  = __floats2half2_rn(bb, 0.0f);

        ppA[i] = make_float4(u, v, Af, Bf);
        ppB[i] = make_float4(Cf, osig, prg.f, pb.f);
    }

    // ---- phase 2: parallel rank sort (16 threads/item, shfl-reduce) ----
    {
        int sub = t & 15;
        for (int i = t >> 4; i < L; i += 64) {
            unsigned long long ki = zk[i];
            int r = 0;
            for (int j = sub; j < L; j += 16) r += (zk[j] < ki) ? 1 : 0;
            r += __shfl_xor(r, 1);
            r += __shfl_xor(r, 2);
            r += __shfl_xor(r, 4);
            r += __shfl_xor(r, 8);
            if (sub == 0) srt[r] = (unsigned short)i;
        }
    }
    __syncthreads();

    // ---- phase 4: segmented composite via rank->slot indirection ----
    int px = bx * 8 + (lane & 7);
    int py = by * 8 + (lane >> 3);
    float gu = ((float)px - 63.5f) / FOCAL;
    float gv = ((float)py - 63.5f) / FOCAL;

    int s = (L * wave) >> 4;
    int e = (L * (wave + 1)) >> 4;

    float T = 1.0f, cr = 0.0f, cg = 0.0f, cb = 0.0f;
    for (int i = s; i < e; ++i) {
        int slot = srt[i];               // wave-uniform broadcast read
        float4 q0 = ppA[slot];
        float4 q1 = ppB[slot];

        float dx = gu - q0.x;
        float dy = gv - q0.y;
        float t1v = fmaf(q0.w, dy, q0.z * dx);
        float p   = fmaf(t1v, dx, q1.x * (dy * dy));
        p = fminf(p, 0.0f);
        float gw = EXP2F(p);
        float alpha = fminf(q1.y * gw, 0.99f);
        float w = alpha * T;

        union { float f; __half2 h; } crg, cbb;
        crg.f = q1.z; cbb.f = q1.w;
        float2 rgv = __half22float2(crg.h);
        float bch = __low2float(cbb.h);

        cr = fmaf(w, rgv.x, cr);
        cg = fmaf(w, rgv.y, cg);
        cb = fmaf(w, bch, cb);
        T = fmaf(-alpha, T, T);
    }
    seg[wave][lane] = make_float4(cr, cg, cb, T);
    __syncthreads();

    // ordered combine of 16 segments -> output
    if (t < 64) {
        float Tt = 1.0f, r = 0.0f, g = 0.0f, b = 0.0f;
        #pragma unroll
        for (int sgi = 0; sgi < NSEG; ++sgi) {
            float4 v = seg[sgi][t];
            r = fmaf(Tt, v.x, r);
            g = fmaf(Tt, v.y, g);
            b = fmaf(Tt, v.z, b);
            Tt *= v.w;
        }
        int p = py * WW + px;
        out[p * 3 + 0] = r;
        out[p * 3 + 1] = g;
        out[p * 3 + 2] = b;
    }
}

extern "C" void kernel_launch(void* const* d_in, const int* in_sizes, int n_in,
                              void* d_out, int out_size, void* d_ws, size_t ws_size,
                              hipStream_t stream) {
    const float* pos   = (const float*)d_in[0];
    const float* rgb   = (const float*)d_in[1];
    const float* opa   = (const float*)d_in[2];
    const float4* quat = (const float4*)d_in[3];
    const float* scale = (const float*)d_in[4];
    const float* w2c   = (const float*)d_in[5];
    const float* tran  = (const float*)d_in[6];
    float* out = (float*)d_out;

    splat_fused<<<(HH * WW) / 64, 1024, 0, stream>>>(pos, rgb, opa, quat, scale, w2c, tran, out);
}